// Round 2
// baseline (539.583 us; speedup 1.0000x reference)
//
#include <hip/hip_runtime.h>

#define NLEV 8
#define COLS 43   // 8*(2+3)+3
#define TPB 64    // one wave per block: barrier is wave-local, 11 KB LDS -> ~14 blocks/CU

typedef float v4f __attribute__((ext_vector_type(4)));   // native vector: OK for nontemporal builtins

// One thread = one point. Phase 1: compute all 8 hash ids and issue all 8 float2
// gathers back-to-back (max memory-level parallelism). Phase 2: stage weights +
// inputs in LDS while gathers fly. Phase 3: stage feats, then the wave writes its
// 64x43 tile with coalesced NONTEMPORAL float4 stores (output = 360 MB > 256 MB L3;
// nt keeps the 23.4 MB embedding table resident in L3 so gathers stay cache hits).
__global__ __launch_bounds__(TPB) void hashgrid_kernel(
    const float* __restrict__ inputs,   // [N,3]
    const float2* __restrict__ emb,     // [2920448,2] viewed as float2
    float* __restrict__ out,            // [N,43]
    int N)
{
    __shared__ __align__(16) float lds[TPB * COLS];   // 11008 B
    const int tid = threadIdx.x;
    const int i = blockIdx.x * TPB + tid;

    // per-level cumulative start offsets and pow2 size masks
    // sizes: 4096, 32768, 262144, 524288 x5  (all pow2 -> mod == and)
    const unsigned off_c[NLEV]  = {0u, 4096u, 36864u, 299008u,
                                   823296u, 1347584u, 1871872u, 2396160u};
    const unsigned mask_c[NLEV] = {4095u, 32767u, 262143u, 524287u,
                                   524287u, 524287u, 524287u, 524287u};

    if (i < N) {
        const float x0 = inputs[3 * i + 0];
        const float x1 = inputs[3 * i + 1];
        const float x2 = inputs[3 * i + 2];

        // ---- Phase 1: all hashes, then all gathers issued back-to-back ----
        unsigned id[NLEV];
        float ga[NLEV], gb[NLEV], gc[NLEV];
        bool  ma[NLEV], mb[NLEV], mc[NLEV];
        #pragma unroll
        for (int L = 0; L < NLEV; ++L) {
            const float res = (float)(16 << L);
            const float a = x0 * res, b = x1 * res, c = x2 * res;
            const float fa = floorf(a), fb = floorf(b), fc = floorf(c);
            ga[L] = a - fa; gb[L] = b - fb; gc[L] = c - fc;
            ma[L] = ga[L] < 0.5f; mb[L] = gb[L] < 0.5f; mc[L] = gc[L] < 0.5f;
            const unsigned na = (unsigned)fa + (ma[L] ? 0u : 1u);
            const unsigned nb = (unsigned)fb + (mb[L] ? 0u : 1u);
            const unsigned nc = (unsigned)fc + (mc[L] ? 0u : 1u);
            const unsigned h = na ^ (nb * 2654435761u) ^ (nc * 805459861u);
            id[L] = (h & mask_c[L]) + off_c[L];
        }
        float2 f[NLEV];
        #pragma unroll
        for (int L = 0; L < NLEV; ++L) {
            f[L] = emb[id[L]];              // 8 independent 8B gathers in flight
        }

        // ---- Phase 2: stage weights + inputs while gathers fly ----
        float* row = &lds[tid * COLS];      // stride 43: odd -> 2-way bank alias (free)
        #pragma unroll
        for (int L = 0; L < NLEV; ++L) {
            row[5 * L + 2] = ma[L] ? ga[L] : 1.0f - ga[L];
            row[5 * L + 3] = mb[L] ? gb[L] : 1.0f - gb[L];
            row[5 * L + 4] = mc[L] ? gc[L] : 1.0f - gc[L];
        }
        row[40] = x0;
        row[41] = x1;
        row[42] = x2;

        // ---- Phase 3: stage feats as they arrive ----
        #pragma unroll
        for (int L = 0; L < NLEV; ++L) {
            row[5 * L + 0] = f[L].x;
            row[5 * L + 1] = f[L].y;
        }
    }
    __syncthreads();   // single-wave block: cheap (no cross-wave coupling), orders LDS

    // Coalesced nontemporal tile write-out. Wave tile = 64*43 floats = 688 float4.
    // Tile byte size 11008 is 16B-aligned, so float4 stores are aligned.
    const long long tile_base = (long long)blockIdx.x * (TPB * COLS);
    if ((blockIdx.x + 1) * TPB <= N) {
        v4f* __restrict__ out4 = (v4f*)(out + tile_base);
        const v4f* l4 = (const v4f*)lds;
        const int NV = TPB * COLS / 4;      // 688 = 64*10 + 48
        #pragma unroll
        for (int j = 0; j < 10; ++j) {
            const int k = tid + j * TPB;
            __builtin_nontemporal_store(l4[k], &out4[k]);
        }
        const int k = tid + 10 * TPB;
        if (k < NV) {
            __builtin_nontemporal_store(l4[k], &out4[k]);
        }
    } else {
        // tail block (not hit for N = 2^21, kept for safety)
        const int valid = N - blockIdx.x * TPB;
        const int NT = valid * COLS;
        for (int k = tid; k < NT; k += TPB) {
            out[tile_base + k] = lds[k];
        }
    }
}

extern "C" void kernel_launch(void* const* d_in, const int* in_sizes, int n_in,
                              void* d_out, int out_size, void* d_ws, size_t ws_size,
                              hipStream_t stream) {
    const float*  inputs = (const float*)d_in[0];
    const float2* emb    = (const float2*)d_in[1];
    float* out = (float*)d_out;
    const int N = in_sizes[0] / 3;   // 2097152
    const int grid = (N + TPB - 1) / TPB;
    hashgrid_kernel<<<grid, TPB, 0, stream>>>(inputs, emb, out, N);
}